// Round 6
// baseline (153.374 us; speedup 1.0000x reference)
//
#include <hip/hip_runtime.h>

#define B_ 16
#define T_ 800
#define D_ 256
#define K_ 64
#define NTILE 13     // ceil(800/64) t-tiles

// ---------------- Fused kernel: llk -> softmax -> r (LDS only) -> P atomic, Spart --------
// grid = 16*13 = 208 blocks x 512 thr (8 waves -> 2/SIMD, 1 block/CU, 150 KB LDS).
// Phase 1 (dist GEMM + softmax): thread = (tx=tid>>4 0..31, ky=tid&15):
//   owns t = t0+tx*2+i (i<2), k = ky+16j (j<4). r tile -> LDS rt[t][k-swizzled].
// Phase 2 (pool GEMM): thread = (kx=tid>>5 0..15, dhalf=tid&31):
//   owns k = kx+16j (j<4), d in {dhalf*4..+3} u {128+dhalf*4..+3}; atomicAdd into P.
__global__ __launch_bounds__(512, 1) void kernelAB(
    const float* __restrict__ x, const float* __restrict__ mu,
    const float* __restrict__ prec, float* __restrict__ P, float* __restrict__ Spart)
{
    __shared__ float xs[64 * 260];   // [t][d] pad 260 -> conflict-free
    __shared__ float mus[64 * 260];  // [k][d]
    __shared__ float rt[64 * 68];    // [t][k-slot] pad 68
    __shared__ float xxs[64];
    __shared__ float mms[64];
    __shared__ float sred[8][64];

    const int tid  = threadIdx.x;
    const int tx   = tid >> 4;     // 0..31
    const int ky   = tid & 15;
    const int b    = blockIdx.x / NTILE;
    const int tile = blockIdx.x % NTILE;
    const int t0   = tile * 64;

    // ---- stage full x tile + full mu (each thread: 8 f4 from each) ----
    #pragma unroll
    for (int jj = 0; jj < 8; ++jj) {
        const int g   = tid + jj * 512;      // 0..4095 f4
        const int row = g >> 6, col = g & 63;
        int trow = t0 + row; if (trow > T_ - 1) trow = T_ - 1;
        *(float4*)&xs[row * 260 + col * 4] =
            *(const float4*)(x + ((size_t)(b * T_ + trow)) * D_ + col * 4);
        *(float4*)&mus[row * 260 + col * 4] =
            *(const float4*)(mu + (size_t)row * D_ + col * 4);
    }
    __syncthreads();

    // ---- xx[t], mm[k] ----
    {
        const int srow = tid >> 3, sq = tid & 7;
        float xxp = 0.f, mmp = 0.f;
        #pragma unroll
        for (int m = 0; m < 8; ++m) {
            float4 v = *(const float4*)&xs[srow * 260 + (sq * 8 + m) * 4];
            xxp = fmaf(v.x, v.x, xxp); xxp = fmaf(v.y, v.y, xxp);
            xxp = fmaf(v.z, v.z, xxp); xxp = fmaf(v.w, v.w, xxp);
            float4 u = *(const float4*)&mus[srow * 260 + (sq * 8 + m) * 4];
            mmp = fmaf(u.x, u.x, mmp); mmp = fmaf(u.y, u.y, mmp);
            mmp = fmaf(u.z, u.z, mmp); mmp = fmaf(u.w, u.w, mmp);
        }
        xxp += __shfl_xor(xxp, 1); xxp += __shfl_xor(xxp, 2); xxp += __shfl_xor(xxp, 4);
        mmp += __shfl_xor(mmp, 1); mmp += __shfl_xor(mmp, 2); mmp += __shfl_xor(mmp, 4);
        if (sq == 0) { xxs[srow] = xxp; mms[srow] = mmp; }
    }
    __syncthreads();

    // ---- phase 1 GEMM: 64 dg steps, barrier-free ----
    float acc[2][4];
    #pragma unroll
    for (int i = 0; i < 2; ++i)
        #pragma unroll
        for (int j = 0; j < 4; ++j) acc[i][j] = 0.f;

    #pragma unroll 4
    for (int dg = 0; dg < 64; ++dg) {
        float4 xv[2], mv[4];
        #pragma unroll
        for (int i = 0; i < 2; ++i) xv[i] = *(const float4*)&xs[(tx * 2 + i) * 260 + dg * 4];
        #pragma unroll
        for (int j = 0; j < 4; ++j) mv[j] = *(const float4*)&mus[(ky + 16 * j) * 260 + dg * 4];
        #pragma unroll
        for (int i = 0; i < 2; ++i)
            #pragma unroll
            for (int j = 0; j < 4; ++j) {
                float a = acc[i][j];
                a = fmaf(xv[i].x, mv[j].x, a);
                a = fmaf(xv[i].y, mv[j].y, a);
                a = fmaf(xv[i].z, mv[j].z, a);
                a = fmaf(xv[i].w, mv[j].w, a);
                acc[i][j] = a;
            }
    }

    // ---- softmax over k (16 lanes of same tx hold all 64 k) -> rt tile + S partials ----
    float p2[4], mmk[4];
    #pragma unroll
    for (int j = 0; j < 4; ++j) {
        float p = prec[ky + 16 * j];
        p2[j] = p * p;
        mmk[j] = mms[ky + 16 * j];
    }

    float sacc[4] = {0.f, 0.f, 0.f, 0.f};
    #pragma unroll
    for (int i = 0; i < 2; ++i) {
        const int tl = tx * 2 + i;
        const bool valid = (t0 + tl) < T_;
        const float xxv = xxs[tl];
        float llk[4];
        #pragma unroll
        for (int j = 0; j < 4; ++j)
            llk[j] = p2[j] * (2.f * acc[i][j] - xxv - mmk[j]);
        float mx = fmaxf(fmaxf(llk[0], llk[1]), fmaxf(llk[2], llk[3]));
        mx = fmaxf(mx, __shfl_xor(mx, 1)); mx = fmaxf(mx, __shfl_xor(mx, 2));
        mx = fmaxf(mx, __shfl_xor(mx, 4)); mx = fmaxf(mx, __shfl_xor(mx, 8));
        float e[4], ps = 0.f;
        #pragma unroll
        for (int j = 0; j < 4; ++j) { e[j] = __expf(llk[j] - mx); ps += e[j]; }
        ps += __shfl_xor(ps, 1); ps += __shfl_xor(ps, 2);
        ps += __shfl_xor(ps, 4); ps += __shfl_xor(ps, 8);
        const float inv = valid ? (1.f / ps) : 0.f;   // invalid rows -> r = 0
        float4 rv;
        rv.x = e[0] * inv; rv.y = e[1] * inv; rv.z = e[2] * inv; rv.w = e[3] * inv;
        // k-swizzled: slot ky*4+j holds k = ky+16j
        *(float4*)&rt[tl * 68 + ky * 4] = rv;
        sacc[0] += rv.x; sacc[1] += rv.y; sacc[2] += rv.z; sacc[3] += rv.w;
    }

    #pragma unroll
    for (int j = 0; j < 4; ++j) {
        sacc[j] += __shfl_xor(sacc[j], 16);
        sacc[j] += __shfl_xor(sacc[j], 32);
    }
    const int w = tid >> 6;
    if ((tid & 48) == 0) {
        #pragma unroll
        for (int j = 0; j < 4; ++j) sred[w][ky * 4 + j] = sacc[j];
    }
    __syncthreads();   // rt complete + sred ready
    if (tid < 64) {
        const int k = tid;
        const int slot = (k & 15) * 4 + (k >> 4);
        float s = 0.f;
        #pragma unroll
        for (int q = 0; q < 8; ++q) s += sred[q][slot];
        Spart[((size_t)b * NTILE + tile) * K_ + k] = s;
    }

    // ---- phase 2 GEMM: P[k][d] += sum_t rt[t][k] * xs[t][d] ----
    const int dhalf = tid & 31;       // lanes 0..31 -> consecutive f4 -> conflict-free b128
    const int kx2   = tid >> 5;       // 0..15

    float4 pa[4][2];
    #pragma unroll
    for (int j = 0; j < 4; ++j) {
        pa[j][0] = make_float4(0.f, 0.f, 0.f, 0.f);
        pa[j][1] = make_float4(0.f, 0.f, 0.f, 0.f);
    }

    #pragma unroll 8
    for (int tt = 0; tt < 64; ++tt) {
        const float4 rv  = *(const float4*)&rt[tt * 68 + kx2 * 4];       // k = kx2+16j
        const float4 xv0 = *(const float4*)&xs[tt * 260 + dhalf * 4];
        const float4 xv1 = *(const float4*)&xs[tt * 260 + 128 + dhalf * 4];
        #pragma unroll
        for (int j = 0; j < 4; ++j) {
            const float rj = (j == 0) ? rv.x : (j == 1) ? rv.y : (j == 2) ? rv.z : rv.w;
            pa[j][0].x = fmaf(rj, xv0.x, pa[j][0].x);
            pa[j][0].y = fmaf(rj, xv0.y, pa[j][0].y);
            pa[j][0].z = fmaf(rj, xv0.z, pa[j][0].z);
            pa[j][0].w = fmaf(rj, xv0.w, pa[j][0].w);
            pa[j][1].x = fmaf(rj, xv1.x, pa[j][1].x);
            pa[j][1].y = fmaf(rj, xv1.y, pa[j][1].y);
            pa[j][1].z = fmaf(rj, xv1.z, pa[j][1].z);
            pa[j][1].w = fmaf(rj, xv1.w, pa[j][1].w);
        }
    }

    float* Pb = P + (size_t)b * K_ * D_;
    #pragma unroll
    for (int j = 0; j < 4; ++j) {
        const int k = kx2 + 16 * j;
        float* dst = Pb + (size_t)k * D_ + dhalf * 4;
        atomicAdd(dst + 0, pa[j][0].x);
        atomicAdd(dst + 1, pa[j][0].y);
        atomicAdd(dst + 2, pa[j][0].z);
        atomicAdd(dst + 3, pa[j][0].w);
        atomicAdd(dst + 128, pa[j][1].x);
        atomicAdd(dst + 129, pa[j][1].y);
        atomicAdd(dst + 130, pa[j][1].z);
        atomicAdd(dst + 131, pa[j][1].w);
    }
}

// ---------------- Kernel C: out = P*inv - (S*inv)*mu ----------------
// grid = 256 blocks x 256 thr; one f4 of out per thread
__global__ __launch_bounds__(256) void kernelC(
    const float* __restrict__ P, const float* __restrict__ Spart,
    const float* __restrict__ mu, float* __restrict__ out)
{
    const int o4 = blockIdx.x * 256 + threadIdx.x;   // 0..65535 = ((b*64+k)*64+d4)
    const int d4 = o4 & 63;
    const int k  = (o4 >> 6) & 63;
    const int b  = o4 >> 12;

    float s = 0.f;
    #pragma unroll
    for (int p = 0; p < NTILE; ++p)
        s += Spart[((size_t)b * NTILE + p) * K_ + k];

    const float4 pv = ((const float4*)P)[o4];
    const float inv = 1.f / (s + 1e-9f);
    const float sm  = s * inv;
    const float4 m = ((const float4*)mu)[k * 64 + d4];
    float4 o;
    o.x = pv.x * inv - sm * m.x;
    o.y = pv.y * inv - sm * m.y;
    o.z = pv.z * inv - sm * m.z;
    o.w = pv.w * inv - sm * m.w;
    ((float4*)out)[o4] = o;
}

extern "C" void kernel_launch(void* const* d_in, const int* in_sizes, int n_in,
                              void* d_out, int out_size, void* d_ws, size_t ws_size,
                              hipStream_t stream) {
    const float* x    = (const float*)d_in[0];
    const float* mu   = (const float*)d_in[1];
    const float* prec = (const float*)d_in[2];
    float* out = (float*)d_out;

    float* P     = (float*)d_ws;                      // B*K*D    = 262144 f (4 MB)
    float* Spart = P + (size_t)B_ * K_ * D_;          // B*NTILE*K = 13312 f

    hipMemsetAsync(P, 0, (size_t)B_ * K_ * D_ * sizeof(float), stream);
    kernelAB<<<B_ * NTILE, 512, 0, stream>>>(x, mu, prec, P, Spart);
    kernelC<<<256, 256, 0, stream>>>(P, Spart, mu, out);
}

// Round 7
// 85.012 us; speedup vs baseline: 1.8041x; 1.8041x over previous
//
#include <hip/hip_runtime.h>

#define B_ 16
#define T_ 800
#define D_ 256
#define K_ 64
#define NTILE 13     // ceil(800/64) t-tiles

// ---------------- Fused kernel: llk -> softmax -> r (LDS only) -> Pp partial, Spart ------
// grid = 16*13 = 208 blocks x 512 thr (8 waves -> 2/SIMD, 1 block/CU, 150 KB LDS).
// Phase 1 (dist GEMM + softmax): thread = (tx=tid>>4 0..31, ky=tid&15):
//   owns t = t0+tx*2+i (i<2), k = ky+16j (j<4). r tile -> LDS rt[t][k-swizzled].
// Phase 2 (pool GEMM): thread = (kx2=tid>>5 0..15, dhalf=tid&31):
//   owns k = kx2+16j (j<4), d in {dhalf*4..+3} u {128+dhalf*4..+3}; PLAIN stores to Pp.
__global__ __launch_bounds__(512, 1) void kernelAB(
    const float* __restrict__ x, const float* __restrict__ mu,
    const float* __restrict__ prec, float* __restrict__ Pp, float* __restrict__ Spart)
{
    __shared__ float xs[64 * 260];   // [t][d] pad 260 -> conflict-free
    __shared__ float mus[64 * 260];  // [k][d]
    __shared__ float rt[64 * 68];    // [t][k-slot] pad 68
    __shared__ float xxs[64];
    __shared__ float mms[64];
    __shared__ float sred[8][64];

    const int tid  = threadIdx.x;
    const int tx   = tid >> 4;     // 0..31
    const int ky   = tid & 15;
    const int b    = blockIdx.x / NTILE;
    const int tile = blockIdx.x % NTILE;
    const int t0   = tile * 64;

    // ---- stage full x tile + full mu (each thread: 8 f4 from each) ----
    #pragma unroll
    for (int jj = 0; jj < 8; ++jj) {
        const int g   = tid + jj * 512;      // 0..4095 f4
        const int row = g >> 6, col = g & 63;
        int trow = t0 + row; if (trow > T_ - 1) trow = T_ - 1;
        *(float4*)&xs[row * 260 + col * 4] =
            *(const float4*)(x + ((size_t)(b * T_ + trow)) * D_ + col * 4);
        *(float4*)&mus[row * 260 + col * 4] =
            *(const float4*)(mu + (size_t)row * D_ + col * 4);
    }
    __syncthreads();

    // ---- xx[t], mm[k] ----
    {
        const int srow = tid >> 3, sq = tid & 7;
        float xxp = 0.f, mmp = 0.f;
        #pragma unroll
        for (int m = 0; m < 8; ++m) {
            float4 v = *(const float4*)&xs[srow * 260 + (sq * 8 + m) * 4];
            xxp = fmaf(v.x, v.x, xxp); xxp = fmaf(v.y, v.y, xxp);
            xxp = fmaf(v.z, v.z, xxp); xxp = fmaf(v.w, v.w, xxp);
            float4 u = *(const float4*)&mus[srow * 260 + (sq * 8 + m) * 4];
            mmp = fmaf(u.x, u.x, mmp); mmp = fmaf(u.y, u.y, mmp);
            mmp = fmaf(u.z, u.z, mmp); mmp = fmaf(u.w, u.w, mmp);
        }
        xxp += __shfl_xor(xxp, 1); xxp += __shfl_xor(xxp, 2); xxp += __shfl_xor(xxp, 4);
        mmp += __shfl_xor(mmp, 1); mmp += __shfl_xor(mmp, 2); mmp += __shfl_xor(mmp, 4);
        if (sq == 0) { xxs[srow] = xxp; mms[srow] = mmp; }
    }
    __syncthreads();

    // ---- phase 1 GEMM: 64 dg steps, barrier-free (xv/mv reads are broadcast -> cheap) ----
    float acc[2][4];
    #pragma unroll
    for (int i = 0; i < 2; ++i)
        #pragma unroll
        for (int j = 0; j < 4; ++j) acc[i][j] = 0.f;

    #pragma unroll 4
    for (int dg = 0; dg < 64; ++dg) {
        float4 xv[2], mv[4];
        #pragma unroll
        for (int i = 0; i < 2; ++i) xv[i] = *(const float4*)&xs[(tx * 2 + i) * 260 + dg * 4];
        #pragma unroll
        for (int j = 0; j < 4; ++j) mv[j] = *(const float4*)&mus[(ky + 16 * j) * 260 + dg * 4];
        #pragma unroll
        for (int i = 0; i < 2; ++i)
            #pragma unroll
            for (int j = 0; j < 4; ++j) {
                float a = acc[i][j];
                a = fmaf(xv[i].x, mv[j].x, a);
                a = fmaf(xv[i].y, mv[j].y, a);
                a = fmaf(xv[i].z, mv[j].z, a);
                a = fmaf(xv[i].w, mv[j].w, a);
                acc[i][j] = a;
            }
    }

    // ---- softmax over k (16 lanes of same tx hold all 64 k) -> rt tile + S partials ----
    float p2[4], mmk[4];
    #pragma unroll
    for (int j = 0; j < 4; ++j) {
        float p = prec[ky + 16 * j];
        p2[j] = p * p;
        mmk[j] = mms[ky + 16 * j];
    }

    float sacc[4] = {0.f, 0.f, 0.f, 0.f};
    #pragma unroll
    for (int i = 0; i < 2; ++i) {
        const int tl = tx * 2 + i;
        const bool valid = (t0 + tl) < T_;
        const float xxv = xxs[tl];
        float llk[4];
        #pragma unroll
        for (int j = 0; j < 4; ++j)
            llk[j] = p2[j] * (2.f * acc[i][j] - xxv - mmk[j]);
        float mx = fmaxf(fmaxf(llk[0], llk[1]), fmaxf(llk[2], llk[3]));
        mx = fmaxf(mx, __shfl_xor(mx, 1)); mx = fmaxf(mx, __shfl_xor(mx, 2));
        mx = fmaxf(mx, __shfl_xor(mx, 4)); mx = fmaxf(mx, __shfl_xor(mx, 8));
        float e[4], ps = 0.f;
        #pragma unroll
        for (int j = 0; j < 4; ++j) { e[j] = __expf(llk[j] - mx); ps += e[j]; }
        ps += __shfl_xor(ps, 1); ps += __shfl_xor(ps, 2);
        ps += __shfl_xor(ps, 4); ps += __shfl_xor(ps, 8);
        const float inv = valid ? (1.f / ps) : 0.f;   // invalid rows -> r = 0
        float4 rv;
        rv.x = e[0] * inv; rv.y = e[1] * inv; rv.z = e[2] * inv; rv.w = e[3] * inv;
        // k-swizzled: slot ky*4+j holds k = ky+16j
        *(float4*)&rt[tl * 68 + ky * 4] = rv;
        sacc[0] += rv.x; sacc[1] += rv.y; sacc[2] += rv.z; sacc[3] += rv.w;
    }

    #pragma unroll
    for (int j = 0; j < 4; ++j) {
        sacc[j] += __shfl_xor(sacc[j], 16);
        sacc[j] += __shfl_xor(sacc[j], 32);
    }
    const int w = tid >> 6;
    if ((tid & 48) == 0) {
        #pragma unroll
        for (int j = 0; j < 4; ++j) sred[w][ky * 4 + j] = sacc[j];
    }
    __syncthreads();   // rt complete + sred ready
    if (tid < 64) {
        const int k = tid;
        const int slot = (k & 15) * 4 + (k >> 4);
        float s = 0.f;
        #pragma unroll
        for (int q = 0; q < 8; ++q) s += sred[q][slot];
        Spart[((size_t)b * NTILE + tile) * K_ + k] = s;
    }

    // ---- phase 2 GEMM: Pp[b,tile][k][d] = sum_t rt[t][k] * xs[t][d]; plain stores ----
    const int dhalf = tid & 31;       // lanes 0..31 -> consecutive f4 -> conflict-free b128
    const int kx2   = tid >> 5;       // 0..15

    float4 pa[4][2];
    #pragma unroll
    for (int j = 0; j < 4; ++j) {
        pa[j][0] = make_float4(0.f, 0.f, 0.f, 0.f);
        pa[j][1] = make_float4(0.f, 0.f, 0.f, 0.f);
    }

    #pragma unroll 8
    for (int tt = 0; tt < 64; ++tt) {
        const float4 rv  = *(const float4*)&rt[tt * 68 + kx2 * 4];       // k = kx2+16j
        const float4 xv0 = *(const float4*)&xs[tt * 260 + dhalf * 4];
        const float4 xv1 = *(const float4*)&xs[tt * 260 + 128 + dhalf * 4];
        #pragma unroll
        for (int j = 0; j < 4; ++j) {
            const float rj = (j == 0) ? rv.x : (j == 1) ? rv.y : (j == 2) ? rv.z : rv.w;
            pa[j][0].x = fmaf(rj, xv0.x, pa[j][0].x);
            pa[j][0].y = fmaf(rj, xv0.y, pa[j][0].y);
            pa[j][0].z = fmaf(rj, xv0.z, pa[j][0].z);
            pa[j][0].w = fmaf(rj, xv0.w, pa[j][0].w);
            pa[j][1].x = fmaf(rj, xv1.x, pa[j][1].x);
            pa[j][1].y = fmaf(rj, xv1.y, pa[j][1].y);
            pa[j][1].z = fmaf(rj, xv1.z, pa[j][1].z);
            pa[j][1].w = fmaf(rj, xv1.w, pa[j][1].w);
        }
    }

    float* Pb = Pp + ((size_t)(b * NTILE + tile)) * K_ * D_;
    #pragma unroll
    for (int j = 0; j < 4; ++j) {
        const int k = kx2 + 16 * j;
        float* dst = Pb + (size_t)k * D_ + dhalf * 4;
        *(float4*)(dst)       = pa[j][0];
        *(float4*)(dst + 128) = pa[j][1];
    }
}

// ---------------- Kernel C: out = (sum_tile Pp)*inv - (S*inv)*mu ----------------
// grid = 256 blocks x 256 thr; one f4 of out per thread
__global__ __launch_bounds__(256) void kernelC(
    const float* __restrict__ Pp, const float* __restrict__ Spart,
    const float* __restrict__ mu, float* __restrict__ out)
{
    const int o4 = blockIdx.x * 256 + threadIdx.x;   // 0..65535 = ((b*64+k)*64+d4)
    const int d4 = o4 & 63;
    const int k  = (o4 >> 6) & 63;
    const int b  = o4 >> 12;

    float s = 0.f;
    #pragma unroll
    for (int p = 0; p < NTILE; ++p)
        s += Spart[((size_t)b * NTILE + p) * K_ + k];

    float4 acc = make_float4(0.f, 0.f, 0.f, 0.f);
    #pragma unroll
    for (int p = 0; p < NTILE; ++p) {
        float4 v = ((const float4*)Pp)[((size_t)(b * NTILE + p) * K_ + k) * (D_ / 4) + d4];
        acc.x += v.x; acc.y += v.y; acc.z += v.z; acc.w += v.w;
    }
    const float inv = 1.f / (s + 1e-9f);
    const float sm  = s * inv;
    const float4 m = ((const float4*)mu)[k * 64 + d4];
    float4 o;
    o.x = acc.x * inv - sm * m.x;
    o.y = acc.y * inv - sm * m.y;
    o.z = acc.z * inv - sm * m.z;
    o.w = acc.w * inv - sm * m.w;
    ((float4*)out)[o4] = o;
}

extern "C" void kernel_launch(void* const* d_in, const int* in_sizes, int n_in,
                              void* d_out, int out_size, void* d_ws, size_t ws_size,
                              hipStream_t stream) {
    const float* x    = (const float*)d_in[0];
    const float* mu   = (const float*)d_in[1];
    const float* prec = (const float*)d_in[2];
    float* out = (float*)d_out;

    float* Pp    = (float*)d_ws;                      // B*NTILE*K*D = 3407872 f (13.3 MB)
    float* Spart = Pp + (size_t)B_ * NTILE * K_ * D_; // B*NTILE*K   = 13312 f

    kernelAB<<<B_ * NTILE, 512, 0, stream>>>(x, mu, prec, Pp, Spart);
    kernelC<<<256, 256, 0, stream>>>(Pp, Spart, mu, out);
}

// Round 10
// 80.272 us; speedup vs baseline: 1.9107x; 1.0591x over previous
//
#include <hip/hip_runtime.h>

#define B_ 16
#define T_ 800
#define D_ 256
#define K_ 64
#define NTILE 13

typedef __attribute__((ext_vector_type(8))) short short8v;
typedef __attribute__((ext_vector_type(4))) float f32x4v;

__device__ __forceinline__ ushort bf16rn(float v) {
    unsigned int b = __float_as_uint(v);
    return (ushort)((b + 0x7fffu + ((b >> 16) & 1u)) >> 16);
}
__device__ __forceinline__ float bf16hi(ushort h) {
    return __uint_as_float(((unsigned int)h) << 16);
}

// ---------------- prep: xx[row] = ||x_row||^2, mm[k] = ||mu_k||^2, p2 = prec^2 ------------
__global__ __launch_bounds__(256) void prep(
    const float* __restrict__ x, const float* __restrict__ mu, const float* __restrict__ prec,
    float* __restrict__ xx_g, float* __restrict__ mm_g, float* __restrict__ p2_g)
{
    const int bid = blockIdx.x, tid = threadIdx.x;
    if (bid < 3200) {
        const int row = bid * 4 + (tid >> 6), lane = tid & 63;
        float4 v = ((const float4*)x)[(size_t)row * 64 + lane];
        float s = v.x*v.x + v.y*v.y + v.z*v.z + v.w*v.w;
        #pragma unroll
        for (int off = 32; off > 0; off >>= 1) s += __shfl_xor(s, off);
        if (lane == 0) xx_g[row] = s;
    } else if (bid < 3216) {
        const int row = (bid - 3200) * 4 + (tid >> 6), lane = tid & 63;
        float4 v = ((const float4*)mu)[(size_t)row * 64 + lane];
        float s = v.x*v.x + v.y*v.y + v.z*v.z + v.w*v.w;
        #pragma unroll
        for (int off = 32; off > 0; off >>= 1) s += __shfl_xor(s, off);
        if (lane == 0) mm_g[row] = s;
    } else {
        if (tid < 64) { float p = prec[tid]; p2_g[tid] = p * p; }
    }
}

// ---------------- Fused MFMA kernel ----------------
// grid = 16*13 = 208 blocks x 256 thr (4 waves). Tile 64t x 64k x 256d.
// Phase 1: dot = x . mu^T via 3-product bf16 split MFMA (16x16x32).
// Softmax over k in-wave -> rtT[k][t] bf16. Transpose xh/xl -> xhT/xlT (reusing mu LDS).
// Phase 2: Pp[k][d] = rtT . xT via 2-product split MFMA; plain f32 stores (no atomics).
__global__ __launch_bounds__(256, 1) void kernelAB(
    const float* __restrict__ x, const float* __restrict__ mu,
    const float* __restrict__ xx_g, const float* __restrict__ mm_g,
    const float* __restrict__ p2_g,
    float* __restrict__ Pp, float* __restrict__ Spart)
{
    __shared__ ushort xh_s[64 * 264];    // [t][d] pad 264, bf16 hi
    __shared__ ushort xl_s[64 * 264];    // bf16 lo residual
    __shared__ ushort muh_s[64 * 264];   // phase2 reuse: xhT [256 d][64 t] XOR-swizzled
    __shared__ ushort mul_s[64 * 264];   // phase2 reuse: xlT
    __shared__ ushort rtT_s[64 * 72];    // [k][t] pad 72, bf16
    __shared__ float xxs[64], mms[64], p2s[64];
    __shared__ float sred[4][64];

    const int tid  = threadIdx.x;
    const int lane = tid & 63;
    const int w    = tid >> 6;       // wave index
    const int m    = lane & 15;
    const int q    = lane >> 4;      // quad
    const int b    = blockIdx.x / NTILE;
    const int tile = blockIdx.x % NTILE;
    const int t0   = tile * 64;

    if (tid < 64)       xxs[tid]       = xx_g[b * T_ + min(t0 + tid, T_ - 1)];
    else if (tid < 128) mms[tid - 64]  = mm_g[tid - 64];
    else if (tid < 192) p2s[tid - 128] = p2_g[tid - 128];

    // ---- stage + convert x tile and mu to bf16 hi/lo (64 rows x 64 f4 each) ----
    #pragma unroll 4
    for (int jj = 0; jj < 16; ++jj) {
        const int idx = tid + jj * 256;          // 0..4095 f4
        const int row = idx >> 6, c = idx & 63;  // 64 f4 per 256-float row
        int trow = t0 + row; if (trow > T_ - 1) trow = T_ - 1;
        float4 v = ((const float4*)x)[(size_t)(b * T_ + trow) * 64 + c];
        ushort4 h, l;
        h.x = bf16rn(v.x); l.x = bf16rn(v.x - bf16hi(h.x));
        h.y = bf16rn(v.y); l.y = bf16rn(v.y - bf16hi(h.y));
        h.z = bf16rn(v.z); l.z = bf16rn(v.z - bf16hi(h.z));
        h.w = bf16rn(v.w); l.w = bf16rn(v.w - bf16hi(h.w));
        *(ushort4*)&xh_s[row * 264 + c * 4] = h;
        *(ushort4*)&xl_s[row * 264 + c * 4] = l;
    }
    #pragma unroll 4
    for (int jj = 0; jj < 16; ++jj) {
        const int idx = tid + jj * 256;
        const int row = idx >> 6, c = idx & 63;
        float4 v = ((const float4*)mu)[(size_t)row * 64 + c];
        ushort4 h, l;
        h.x = bf16rn(v.x); l.x = bf16rn(v.x - bf16hi(h.x));
        h.y = bf16rn(v.y); l.y = bf16rn(v.y - bf16hi(h.y));
        h.z = bf16rn(v.z); l.z = bf16rn(v.z - bf16hi(h.z));
        h.w = bf16rn(v.w); l.w = bf16rn(v.w - bf16hi(h.w));
        *(ushort4*)&muh_s[row * 264 + c * 4] = h;
        *(ushort4*)&mul_s[row * 264 + c * 4] = l;
    }
    __syncthreads();

    // ---- phase 1: dot[t][k]; A = x rows (m=t), B = mu rows (n=k), contraction = d ----
    f32x4v acc[4];
    #pragma unroll
    for (int nt = 0; nt < 4; ++nt) acc[nt] = (f32x4v){0.f, 0.f, 0.f, 0.f};

    #pragma unroll 2
    for (int c = 0; c < 8; ++c) {
        const int ao = (w * 16 + m) * 264 + c * 32 + q * 8;
        short8v ah = *(const short8v*)&xh_s[ao];
        short8v al = *(const short8v*)&xl_s[ao];
        #pragma unroll
        for (int nt = 0; nt < 4; ++nt) {
            const int bo = (nt * 16 + m) * 264 + c * 32 + q * 8;
            short8v bh = *(const short8v*)&muh_s[bo];
            short8v bl = *(const short8v*)&mul_s[bo];
            acc[nt] = __builtin_amdgcn_mfma_f32_16x16x32_bf16(ah, bh, acc[nt], 0, 0, 0);
            acc[nt] = __builtin_amdgcn_mfma_f32_16x16x32_bf16(ah, bl, acc[nt], 0, 0, 0);
            acc[nt] = __builtin_amdgcn_mfma_f32_16x16x32_bf16(al, bh, acc[nt], 0, 0, 0);
        }
    }

    // ---- softmax over k: D[m=t: q*4+r][n=k: lane&15]; k spans nt x 16 lanes ----
    float mmk[4], p2k[4];
    #pragma unroll
    for (int nt = 0; nt < 4; ++nt) { mmk[nt] = mms[nt * 16 + m]; p2k[nt] = p2s[nt * 16 + m]; }

    ushort4 rp[4];
    float sacc[4] = {0.f, 0.f, 0.f, 0.f};
    #pragma unroll
    for (int r = 0; r < 4; ++r) {
        const int tl = w * 16 + q * 4 + r;
        const float xxv = xxs[tl];
        const bool valid = (t0 + tl) < T_;
        float llk[4];
        #pragma unroll
        for (int nt = 0; nt < 4; ++nt)
            llk[nt] = p2k[nt] * (2.f * acc[nt][r] - xxv - mmk[nt]);
        float mx = fmaxf(fmaxf(llk[0], llk[1]), fmaxf(llk[2], llk[3]));
        mx = fmaxf(mx, __shfl_xor(mx, 1)); mx = fmaxf(mx, __shfl_xor(mx, 2));
        mx = fmaxf(mx, __shfl_xor(mx, 4)); mx = fmaxf(mx, __shfl_xor(mx, 8));
        float e[4], ps = 0.f;
        #pragma unroll
        for (int nt = 0; nt < 4; ++nt) { e[nt] = __expf(llk[nt] - mx); ps += e[nt]; }
        ps += __shfl_xor(ps, 1); ps += __shfl_xor(ps, 2);
        ps += __shfl_xor(ps, 4); ps += __shfl_xor(ps, 8);
        const float inv = valid ? (1.f / ps) : 0.f;
        #pragma unroll
        for (int nt = 0; nt < 4; ++nt) {
            float rv = e[nt] * inv;
            sacc[nt] += rv;
            ((ushort*)&rp[nt])[r] = bf16rn(rv);
        }
    }
    #pragma unroll
    for (int nt = 0; nt < 4; ++nt)
        *(ushort4*)&rtT_s[(nt * 16 + m) * 72 + w * 16 + q * 4] = rp[nt];
    #pragma unroll
    for (int nt = 0; nt < 4; ++nt) {
        sacc[nt] += __shfl_xor(sacc[nt], 16);
        sacc[nt] += __shfl_xor(sacc[nt], 32);
    }
    if (q == 0) {
        #pragma unroll
        for (int nt = 0; nt < 4; ++nt) sred[w][nt * 16 + m] = sacc[nt];
    }
    __syncthreads();   // phase-1 muh/mul reads done; rtT + sred complete

    if (tid < 64) {
        float s = sred[0][tid] + sred[1][tid] + sred[2][tid] + sred[3][tid];
        Spart[((size_t)b * NTILE + tile) * K_ + tid] = s;
    }

    // ---- transpose xh/xl -> xhT/xlT over muh_s/mul_s; [256 d][32 t-pair words] ----
    // logical word tp at d-row stored at widx = (tp&3) + 4*((tp>>2)^(d&7));
    // stores are same-typed ushort2 (no cross-type aliasing).
    {
        const int tp = tid & 31, dg = tid >> 5;   // t-pair, 32-d group
        #pragma unroll
        for (int c = 0; c < 4; ++c) {
            short8v a0 = *(const short8v*)&xh_s[(2 * tp)     * 264 + dg * 32 + c * 8];
            short8v a1 = *(const short8v*)&xh_s[(2 * tp + 1) * 264 + dg * 32 + c * 8];
            short8v b0 = *(const short8v*)&xl_s[(2 * tp)     * 264 + dg * 32 + c * 8];
            short8v b1 = *(const short8v*)&xl_s[(2 * tp + 1) * 264 + dg * 32 + c * 8];
            #pragma unroll
            for (int j = 0; j < 8; ++j) {
                const int d = dg * 32 + c * 8 + j;
                const int widx = (tp & 3) + 4 * ((tp >> 2) ^ (d & 7));
                ushort2 hv, lv;
                hv.x = (ushort)a0[j]; hv.y = (ushort)a1[j];
                lv.x = (ushort)b0[j]; lv.y = (ushort)b1[j];
                *(ushort2*)&muh_s[d * 64 + widx * 2] = hv;
                *(ushort2*)&mul_s[d * 64 + widx * 2] = lv;
            }
        }
    }
    __syncthreads();

    // ---- phase 2: P[k][d] = sum_t r[t][k] x[t][d]; A = rtT (m=k), B = xT rows (n=d) ----
    f32x4v acc2[16];
    #pragma unroll
    for (int nt = 0; nt < 16; ++nt) acc2[nt] = (f32x4v){0.f, 0.f, 0.f, 0.f};

    #pragma unroll
    for (int tc = 0; tc < 2; ++tc) {
        short8v ar = *(const short8v*)&rtT_s[(w * 16 + m) * 72 + tc * 32 + q * 8];
        #pragma unroll
        for (int nt = 0; nt < 16; ++nt) {
            const int drow = nt * 16 + m;
            const int eoff = ((tc * 4 + q) ^ (drow & 7)) * 8;   // swizzled 8-elem block
            short8v bh = *(const short8v*)&muh_s[drow * 64 + eoff];
            short8v bl = *(const short8v*)&mul_s[drow * 64 + eoff];
            acc2[nt] = __builtin_amdgcn_mfma_f32_16x16x32_bf16(ar, bh, acc2[nt], 0, 0, 0);
            acc2[nt] = __builtin_amdgcn_mfma_f32_16x16x32_bf16(ar, bl, acc2[nt], 0, 0, 0);
        }
    }

    // store: D[m=k: q*4+r][n=d: lane&15]
    float* Pb = Pp + ((size_t)(b * NTILE + tile)) * K_ * D_;
    #pragma unroll
    for (int nt = 0; nt < 16; ++nt) {
        #pragma unroll
        for (int r = 0; r < 4; ++r)
            Pb[(size_t)(w * 16 + q * 4 + r) * D_ + nt * 16 + m] = acc2[nt][r];
    }
}

// ---------------- Kernel C: out = (sum_tile Pp)*inv - (S*inv)*mu ----------------
__global__ __launch_bounds__(256) void kernelC(
    const float* __restrict__ Pp, const float* __restrict__ Spart,
    const float* __restrict__ mu, float* __restrict__ out)
{
    const int o4 = blockIdx.x * 256 + threadIdx.x;   // ((b*64+k)*64+d4)
    const int d4 = o4 & 63;
    const int k  = (o4 >> 6) & 63;
    const int b  = o4 >> 12;

    float s = 0.f;
    #pragma unroll
    for (int p = 0; p < NTILE; ++p)
        s += Spart[((size_t)b * NTILE + p) * K_ + k];

    float4 acc = make_float4(0.f, 0.f, 0.f, 0.f);
    #pragma unroll
    for (int p = 0; p < NTILE; ++p) {
        float4 v = ((const float4*)Pp)[((size_t)(b * NTILE + p) * K_ + k) * (D_ / 4) + d4];
        acc.x += v.x; acc.y += v.y; acc.z += v.z; acc.w += v.w;
    }
    const float inv = 1.f / (s + 1e-9f);
    const float sm  = s * inv;
    const float4 m = ((const float4*)mu)[k * 64 + d4];
    float4 o;
    o.x = acc.x * inv - sm * m.x;
    o.y = acc.y * inv - sm * m.y;
    o.z = acc.z * inv - sm * m.z;
    o.w = acc.w * inv - sm * m.w;
    ((float4*)out)[o4] = o;
}

extern "C" void kernel_launch(void* const* d_in, const int* in_sizes, int n_in,
                              void* d_out, int out_size, void* d_ws, size_t ws_size,
                              hipStream_t stream) {
    const float* x    = (const float*)d_in[0];
    const float* mu   = (const float*)d_in[1];
    const float* prec = (const float*)d_in[2];
    float* out = (float*)d_out;

    float* Pp    = (float*)d_ws;                       // 208*64*256 f = 13.6 MB
    float* Spart = Pp + (size_t)B_ * NTILE * K_ * D_;  // 13312 f
    float* xx_g  = Spart + (size_t)B_ * NTILE * K_;    // 12800 f
    float* mm_g  = xx_g + (size_t)B_ * T_;             // 64 f
    float* p2_g  = mm_g + 64;                          // 64 f

    prep<<<3217, 256, 0, stream>>>(x, mu, prec, xx_g, mm_g, p2_g);
    kernelAB<<<B_ * NTILE, 256, 0, stream>>>(x, mu, xx_g, mm_g, p2_g, Pp, Spart);
    kernelC<<<256, 256, 0, stream>>>(Pp, Spart, mu, out);
}